// Round 1
// baseline (129.530 us; speedup 1.0000x reference)
//
#include <hip/hip_runtime.h>
#include <math.h>

#define MARGIN 1.9f

// ---------------------------------------------------------------------------
// K0: squared norms per row
// ---------------------------------------------------------------------------
__global__ void sqnorm_kernel(const float* __restrict__ e, float* __restrict__ sq,
                              int n, int d) {
    int j = blockIdx.x * blockDim.x + threadIdx.x;
    if (j >= n) return;
    const float* row = e + (size_t)j * d;
    float s = 0.f;
    int d4 = d >> 2;
    const float4* r4 = (const float4*)row;
    for (int t = 0; t < d4; ++t) {
        float4 a = r4[t];
        s += a.x * a.x + a.y * a.y + a.z * a.z + a.w * a.w;
    }
    for (int t = d4 << 2; t < d; ++t) s += row[t] * row[t];
    sq[j] = s;
}

// ---------------------------------------------------------------------------
// K1: pairwise Euclidean distances, one block per row i
// dist[i][j] = (v==0) ? 0 : sqrt(v),  v = relu(sq_i - 2*dot + sq_j)
// ---------------------------------------------------------------------------
__global__ void dist_kernel(const float* __restrict__ e, const float* __restrict__ sq,
                            float* __restrict__ dist, int n, int d) {
    __shared__ float ei[512];  // d <= 512 (here d=128)
    int i = blockIdx.x;
    for (int t = threadIdx.x; t < d; t += blockDim.x) ei[t] = e[(size_t)i * d + t];
    __syncthreads();
    float sqi = sq[i];
    int d4 = d >> 2;
    const float4* ei4 = (const float4*)ei;
    for (int j = threadIdx.x; j < n; j += blockDim.x) {
        const float* rj = e + (size_t)j * d;
        const float4* rj4 = (const float4*)rj;
        float dot = 0.f;
        for (int t = 0; t < d4; ++t) {
            float4 a = ei4[t];
            float4 b = rj4[t];
            dot += a.x * b.x + a.y * b.y + a.z * b.z + a.w * b.w;
        }
        for (int t = d4 << 2; t < d; ++t) dot += ei[t] * rj[t];
        float v = sqi - 2.f * dot + sq[j];
        v = v > 0.f ? v : 0.f;
        dist[(size_t)i * n + j] = (v == 0.f) ? 0.f : sqrtf(v);
    }
}

// ---------------------------------------------------------------------------
// K2: per-anchor triplet sweep. One block per anchor i.
// total += sum_{j in P_i, k in N_i} relu(d_ij - d_ik + margin)
// cnt_ne += #{strictly positive};  cnt_valid += |P_i|*|N_i|
// ---------------------------------------------------------------------------
__global__ void triplet_kernel(const float* __restrict__ dist, const int* __restrict__ lab,
                               int n, float* __restrict__ total,
                               unsigned long long* __restrict__ cnt_ne,
                               unsigned long long* __restrict__ cnt_valid) {
    extern __shared__ float smem[];
    float* row = smem;               // n floats: dist row i
    float* pos = smem + n;           // n floats: positive distances
    float* neg = smem + 2 * n;       // n floats: negative distances
    int* labs = (int*)(smem + 3 * n);// n ints
    __shared__ int p_cnt, n_cnt;
    __shared__ float red_s[8];
    __shared__ unsigned int red_c[8];

    int i = blockIdx.x;
    int tid = threadIdx.x;
    if (tid == 0) { p_cnt = 0; n_cnt = 0; }
    for (int j = tid; j < n; j += blockDim.x) {
        row[j] = dist[(size_t)i * n + j];
        labs[j] = lab[j];
    }
    __syncthreads();
    int my_lab = labs[i];
    for (int j = tid; j < n; j += blockDim.x) {
        int lj = labs[j];
        if (lj == my_lab) {
            if (j != i) { int idx = atomicAdd(&p_cnt, 1); pos[idx] = row[j]; }
        } else {
            int idx = atomicAdd(&n_cnt, 1); neg[idx] = row[j];
        }
    }
    __syncthreads();
    int P = p_cnt, N = n_cnt;

    float sum = 0.f;
    unsigned int c = 0;
    for (int j = 0; j < P; ++j) {
        float a = pos[j] + MARGIN;
        for (int k = tid; k < N; k += blockDim.x) {
            float t = a - neg[k];
            if (t > 0.f) { sum += t; c++; }
        }
    }

    // wave (64-lane) shuffle reduction
    for (int off = 32; off > 0; off >>= 1) {
        sum += __shfl_down(sum, off, 64);
        c += __shfl_down(c, off, 64);
    }
    int wave = tid >> 6;
    if ((tid & 63) == 0) { red_s[wave] = sum; red_c[wave] = c; }
    __syncthreads();
    if (tid == 0) {
        int nwaves = (blockDim.x + 63) >> 6;
        float s = 0.f;
        unsigned int cc = 0;
        for (int w = 0; w < nwaves; ++w) { s += red_s[w]; cc += red_c[w]; }
        atomicAdd(total, s);
        atomicAdd(cnt_ne, (unsigned long long)cc);
        atomicAdd(cnt_valid, (unsigned long long)P * (unsigned long long)N);
    }
}

// ---------------------------------------------------------------------------
// K3: finalize -> out[4] = {loss, num_valid, num_non_easy, frac}
// ---------------------------------------------------------------------------
__global__ void finalize_kernel(const float* __restrict__ total,
                                const unsigned long long* __restrict__ cnt_ne,
                                const unsigned long long* __restrict__ cnt_valid,
                                float* __restrict__ out) {
    if (threadIdx.x == 0 && blockIdx.x == 0) {
        float t = *total;
        float ne = (float)(*cnt_ne);
        float nv = (float)(*cnt_valid);
        float loss = (ne > 0.f) ? (t / fmaxf(ne, 1.f)) : 0.f;
        out[0] = loss;
        out[1] = nv;
        out[2] = ne;
        out[3] = ne / (nv + 1e-16f);
    }
}

extern "C" void kernel_launch(void* const* d_in, const int* in_sizes, int n_in,
                              void* d_out, int out_size, void* d_ws, size_t ws_size,
                              hipStream_t stream) {
    const float* e = (const float*)d_in[0];
    const int* lab = (const int*)d_in[1];
    int n = in_sizes[1];           // 8*80 = 640
    int d = in_sizes[0] / n;       // 128

    char* ws = (char*)d_ws;
    float* total = (float*)ws;                                  // offset 0
    unsigned long long* cnt_ne = (unsigned long long*)(ws + 8); // offset 8
    unsigned long long* cnt_valid = (unsigned long long*)(ws + 16);
    float* sq = (float*)(ws + 64);                              // n floats
    size_t dist_off = (64 + (size_t)n * sizeof(float) + 255) & ~(size_t)255;
    float* dist = (float*)(ws + dist_off);                      // n*n floats

    // zero the accumulators (ws is poisoned with 0xAA before every launch)
    hipMemsetAsync(d_ws, 0, 64, stream);

    sqnorm_kernel<<<(n + 255) / 256, 256, 0, stream>>>(e, sq, n, d);
    dist_kernel<<<n, 256, 0, stream>>>(e, sq, dist, n, d);

    size_t smem = (size_t)3 * n * sizeof(float) + (size_t)n * sizeof(int);
    triplet_kernel<<<n, 256, smem, stream>>>(dist, lab, n, total, cnt_ne, cnt_valid);
    finalize_kernel<<<1, 64, 0, stream>>>(total, cnt_ne, cnt_valid, (float*)d_out);
}

// Round 2
// 105.489 us; speedup vs baseline: 1.2279x; 1.2279x over previous
//
#include <hip/hip_runtime.h>
#include <math.h>

#define MARGIN 1.9f
#define NMAX 1024   // max rows supported by LDS layout (n=640 here)

// ---------------------------------------------------------------------------
// K1: fully fused per-anchor kernel. One block per anchor i.
//   - stage e_i (d floats) and labels (n ints) in LDS
//   - compute dist row i on the fly: dist_ij = (v==0)?0:sqrt(v),
//       v = relu(||e_i||^2 - 2 e_i.e_j + ||e_j||^2)   (norms computed inline)
//   - compact positives/negatives into LDS lists
//   - sweep P x N pairs: sum relu(d_ij - d_ik + margin), count >0
//   - write per-block partials (no atomics, no pre-zeroed memory needed)
// ---------------------------------------------------------------------------
__global__ __launch_bounds__(256) void fused_triplet_kernel(
        const float* __restrict__ e, const int* __restrict__ lab,
        int n, int d,
        float* __restrict__ part_sum,          // [gridDim]
        unsigned int* __restrict__ part_ne,    // [gridDim]
        unsigned int* __restrict__ part_valid) // [gridDim]
{
    __shared__ float ei[512];          // d <= 512
    __shared__ float pos[NMAX];
    __shared__ float neg[NMAX];
    __shared__ int   labs[NMAX];
    __shared__ int p_cnt, n_cnt;
    __shared__ float red_s[4];
    __shared__ unsigned int red_c[4];

    const int i   = blockIdx.x;
    const int tid = threadIdx.x;

    if (tid == 0) { p_cnt = 0; n_cnt = 0; }
    for (int t = tid; t < d; t += blockDim.x) ei[t] = e[(size_t)i * d + t];
    for (int j = tid; j < n; j += blockDim.x) labs[j] = lab[j];
    __syncthreads();

    // ||e_i||^2 (redundant per-thread from LDS; d=128 -> trivial)
    const int d4 = d >> 2;
    const float4* ei4 = (const float4*)ei;
    float sqi = 0.f;
    for (int t = 0; t < d4; ++t) {
        float4 a = ei4[t];
        sqi += a.x * a.x + a.y * a.y + a.z * a.z + a.w * a.w;
    }
    const int my_lab = labs[i];

    // dist row i + compaction into pos/neg lists
    for (int j = tid; j < n; j += blockDim.x) {
        const float4* rj4 = (const float4*)(e + (size_t)j * d);
        float dot = 0.f, sqj = 0.f;
        for (int t = 0; t < d4; ++t) {
            float4 a = ei4[t];
            float4 b = rj4[t];
            dot += a.x * b.x + a.y * b.y + a.z * b.z + a.w * b.w;
            sqj += b.x * b.x + b.y * b.y + b.z * b.z + b.w * b.w;
        }
        float v = sqi - 2.f * dot + sqj;
        v = v > 0.f ? v : 0.f;
        float dij = (v == 0.f) ? 0.f : sqrtf(v);
        if (labs[j] == my_lab) {
            if (j != i) { int idx = atomicAdd(&p_cnt, 1); pos[idx] = dij; }
        } else {
            int idx = atomicAdd(&n_cnt, 1); neg[idx] = dij;
        }
    }
    __syncthreads();
    const int P = p_cnt, N = n_cnt;

    // sweep: threads own negatives (cached in regs), serial loop over positives
    float myneg[4];  // ceil(NMAX/256) = 4
    int nk = 0;
    for (int k = tid; k < N; k += blockDim.x) myneg[nk++] = neg[k];

    float sum = 0.f;
    unsigned int c = 0;
    for (int j = 0; j < P; ++j) {
        float a = pos[j] + MARGIN;       // LDS broadcast
        for (int r = 0; r < nk; ++r) {
            float t = a - myneg[r];
            if (t > 0.f) { sum += t; c++; }
        }
    }

    // wave-64 shuffle reduction, then cross-wave via LDS
    for (int off = 32; off > 0; off >>= 1) {
        sum += __shfl_down(sum, off, 64);
        c   += __shfl_down(c,   off, 64);
    }
    int wave = tid >> 6;
    if ((tid & 63) == 0) { red_s[wave] = sum; red_c[wave] = c; }
    __syncthreads();
    if (tid == 0) {
        float s = 0.f; unsigned int cc = 0;
        int nwaves = (blockDim.x + 63) >> 6;
        for (int w = 0; w < nwaves; ++w) { s += red_s[w]; cc += red_c[w]; }
        part_sum[i]   = s;
        part_ne[i]    = cc;
        part_valid[i] = (unsigned int)P * (unsigned int)N;
    }
}

// ---------------------------------------------------------------------------
// K2: reduce 640 partials -> out[4] = {loss, num_valid, num_non_easy, frac}
// ---------------------------------------------------------------------------
__global__ __launch_bounds__(256) void finalize_kernel(
        const float* __restrict__ part_sum,
        const unsigned int* __restrict__ part_ne,
        const unsigned int* __restrict__ part_valid,
        int nblk, float* __restrict__ out)
{
    __shared__ float red_s[4];
    __shared__ unsigned long long red_ne[4], red_nv[4];
    int tid = threadIdx.x;

    float s = 0.f;
    unsigned long long ne = 0, nv = 0;
    for (int b = tid; b < nblk; b += blockDim.x) {
        s  += part_sum[b];
        ne += part_ne[b];
        nv += part_valid[b];
    }
    for (int off = 32; off > 0; off >>= 1) {
        s  += __shfl_down(s,  off, 64);
        ne += __shfl_down(ne, off, 64);
        nv += __shfl_down(nv, off, 64);
    }
    int wave = tid >> 6;
    if ((tid & 63) == 0) { red_s[wave] = s; red_ne[wave] = ne; red_nv[wave] = nv; }
    __syncthreads();
    if (tid == 0) {
        float ts = 0.f; unsigned long long tne = 0, tnv = 0;
        int nwaves = (blockDim.x + 63) >> 6;
        for (int w = 0; w < nwaves; ++w) { ts += red_s[w]; tne += red_ne[w]; tnv += red_nv[w]; }
        float fne = (float)tne;
        float fnv = (float)tnv;
        out[0] = (fne > 0.f) ? (ts / fmaxf(fne, 1.f)) : 0.f;
        out[1] = fnv;
        out[2] = fne;
        out[3] = fne / (fnv + 1e-16f);
    }
}

extern "C" void kernel_launch(void* const* d_in, const int* in_sizes, int n_in,
                              void* d_out, int out_size, void* d_ws, size_t ws_size,
                              hipStream_t stream) {
    const float* e  = (const float*)d_in[0];
    const int* lab  = (const int*)d_in[1];
    int n = in_sizes[1];           // 640
    int d = in_sizes[0] / n;       // 128

    // per-block partials in workspace (written before read; no zeroing needed)
    char* ws = (char*)d_ws;
    float*        part_sum   = (float*)ws;
    unsigned int* part_ne    = (unsigned int*)(ws + (size_t)n * 4);
    unsigned int* part_valid = (unsigned int*)(ws + (size_t)n * 8);

    fused_triplet_kernel<<<n, 256, 0, stream>>>(e, lab, n, d,
                                                part_sum, part_ne, part_valid);
    finalize_kernel<<<1, 256, 0, stream>>>(part_sum, part_ne, part_valid,
                                           n, (float*)d_out);
}